// Round 13
// baseline (263.236 us; speedup 1.0000x reference)
//
#include <hip/hip_runtime.h>
#include <hip/hip_bf16.h>

typedef _Float16 f16;
typedef _Float16 half4 __attribute__((ext_vector_type(4)));
typedef float floatx4 __attribute__((ext_vector_type(4)));

// Problem: B=8, C=256, H=W=64, sd=128, HEADS=8, hd=16, window L=256 tokens.
// idx0 = 64x4 column strips (wi = w>>2, t = h*4+(w&3)),
// idx1 = 4x64 row strips   (wi = h>>2, t = (h&3)*64+w).
// Layouts (f16), per idx:
//   qw,kw: head-major [winG*8+head][t(256)][d(16)]
//   vw,ow: c-major [winG(128)][hc(128)][t(256)]      (hc = head*16+d)
// WIN = elems per [idx] tensor = 4194304.
// BOTH shifts live simultaneously (per-shift region stride SSTR f16).
//
// LESSON (r1): XOR swizzle over a non-pow2 padded stride is NOT bijective.
// LESSON (r3/r4/r5): M-split k_proj variants all pathological. M=128 +
// (256,2) is the only well-behaved codegen point. FROZEN at 77.3us.
// LESSON (r8/r9): cvt_pkrtz-via-union blew VGPR 60->152; pattern-fragile
// codegen - scalar (f16) casts are the stable form.
// LESSON (r11/r12): k_attn is VALU-issue-bound (r12: FETCH 148->49MB from
// head-major Q/K, dur only -6%). r13 attacks VALU count: conv in f16
// (weights preconverted in k_prep; kills 144 cvt/thread) + sp layouts
// realigned so center staging is 2x half4 per float4 (was 8 scalar).
#define WIN 4194304
#define SSTR 41943040

// ---- weight prep: wqB[part][kt][nt][lane][kj] (B-frag-ordered);
// block 192: LePE weights/bias -> f16 (wl16[1152], bl16[128])
__global__ void k_prep(const float* __restrict__ wq, const float* __restrict__ wle,
                       const float* __restrict__ ble, f16* __restrict__ wqB,
                       f16* __restrict__ wl16, f16* __restrict__ bl16) {
    if (blockIdx.x == 192) {
        int t = threadIdx.x;
        for (int i = t; i < 1152; i += 256) wl16[i] = (f16)wle[i];
        if (t < 128) bl16[t] = (f16)ble[t];
        return;
    }
    int D = blockIdx.x * 256 + threadIdx.x;
    if (D >= 49152) return;
    int kj = D & 3, lane = (D >> 2) & 63, nt = (D >> 8) & 7;
    int kt = (D >> 11) & 7, part = D >> 14;
    int g = lane >> 4, ln = lane & 15;
    int o = part * 128 + nt * 16 + ln;
    int k = kt * 16 + g * 4 + kj;
    wqB[D] = (f16)wq[o * 128 + k];
}

// ---- MFMA projection, pixel-row tiled: M=128 px (2 h-rows), K=128, N=384
// grid (32 row-pairs, 8 b, 2 idx x 2 shift) = 1024 blocks, 256 threads.
// LDS A-tile: chunked [kc(32)][m(128)][kj(4)] with XOR swizzle
// phys_byte = (kc*1024 + m*8 + kj*2) ^ (((m>>4)&7)<<4)  -> conflict-free
// b128 writes AND contiguous frag reads; bijective (m bits 4..6 live
// untouched in byte bits 7..9).
__global__ __launch_bounds__(256, 2) void k_proj(
    const float* __restrict__ x, const f16* __restrict__ wqB,
    f16* __restrict__ qw, f16* __restrict__ kw, f16* __restrict__ vw)
{
    const int rt = blockIdx.x, b = blockIdx.y;
    const int idx = blockIdx.z & 1, si = blockIdx.z >> 1;
    const int s = si * 2;
    const size_t so = (size_t)si * SSTR;
    const int h0 = rt * 2;
    const int tid = threadIdx.x;
    const int wave = tid >> 6, lane = tid & 63, g = lane >> 4, ln = lane & 15;

    union __align__(16) SM {
        f16 xa[32 * 128 * 4];   // 32 KB  A chunked [kc(32)][m(128)][kj(4)], swizzled
        f16 pt[128 * 136];      // 34.8 KB transpose tile, padded (no swizzle!)
    };
    __shared__ SM sm;

    // stage x -> f16 LDS: per tile, gather 4 c-rows (coalesced float4),
    // register 4x4 transpose, two swizzled b128 stores.
    {
        const int wg = tid & 31;
        const int row = wg >> 4, w4 = (wg & 15) << 2;
        const int gh = (h0 + row + s) & 63;
        const int m0 = row * 64 + w4;
        const unsigned fb = (((unsigned)m0 >> 4) & 7u) << 4;
        const float* xp = x + (((size_t)b * 256) << 12) + (gh << 6) + w4;
        char* lbase = (char*)sm.xa;
        #pragma unroll
        for (int it = 0; it < 4; ++it) {
            int cg = (tid >> 5) + it * 8;
            float4 v4[4];
            #pragma unroll
            for (int cc = 0; cc < 4; ++cc) {
                int gc = (idx * 128 + cg * 4 + cc + s) & 255;
                v4[cc] = *(const float4*)(xp + ((size_t)gc << 12));
            }
            union { half4 h[4]; float4 q[2]; } t;
            #pragma unroll
            for (int jj = 0; jj < 4; ++jj)
                t.h[jj] = (half4){
                    (f16)(((const float*)&v4[0])[jj]),
                    (f16)(((const float*)&v4[1])[jj]),
                    (f16)(((const float*)&v4[2])[jj]),
                    (f16)(((const float*)&v4[3])[jj])};
            char* p = lbase + cg * 1024;
            *(float4*)(p + (((unsigned)(m0 * 8)) ^ fb)) = t.q[0];
            *(float4*)(p + (((unsigned)(m0 * 8 + 16)) ^ fb)) = t.q[1];
        }
    }
    __syncthreads();

    // A-frags (held across parts): A[m=px][k=c], swizzled read (f uniform/instr)
    half4 af[2][8];
    #pragma unroll
    for (int mt = 0; mt < 2; ++mt) {
        int m = wave * 32 + mt * 16 + ln;
        unsigned fb = (((unsigned)m >> 4) & 7u) << 4;
        #pragma unroll
        for (int kt = 0; kt < 8; ++kt) {
            int kc = kt * 4 + g;
            af[mt][kt] = *(const half4*)((char*)sm.xa + kc * 1024 +
                                         (((unsigned)(m * 8)) ^ fb));
        }
    }

    for (int part = 0; part < 3; ++part) {
        floatx4 C[8][2];
        #pragma unroll
        for (int nt = 0; nt < 8; ++nt)
            #pragma unroll
            for (int mt = 0; mt < 2; ++mt) C[nt][mt] = (floatx4){0.f, 0.f, 0.f, 0.f};

        for (int kt = 0; kt < 8; ++kt) {
            half4 bf[8];
            #pragma unroll
            for (int nt = 0; nt < 8; ++nt)
                bf[nt] = *(const half4*)&wqB[((((part * 8 + kt) * 8 + nt) * 64) + lane) * 4];
            #pragma unroll
            for (int nt = 0; nt < 8; ++nt)
                #pragma unroll
                for (int mt = 0; mt < 2; ++mt)
                    C[nt][mt] = __builtin_amdgcn_mfma_f32_16x16x16f16(
                        af[mt][kt], bf[nt], C[nt][mt], 0, 0, 0);
        }

        // q: fold softmax scale AND log2(e) (attn uses exp2)
        const float qsc = (part == 0) ? 0.25f * 1.4426950408889634f : 1.0f;

        __syncthreads();    // xa (part0) / previous pt reads done
        #pragma unroll
        for (int nt = 0; nt < 8; ++nt)
            #pragma unroll
            for (int mt = 0; mt < 2; ++mt)
                #pragma unroll
                for (int r = 0; r < 4; ++r) {
                    int m = wave * 32 + mt * 16 + g * 4 + r;
                    int c = nt * 16 + ln;                 // part-local o
                    int hc = ((c & 7) << 4) + (c >> 3);   // head*16+d
                    f16 hv = (f16)(C[nt][mt][r] * qsc);
                    if (part == 2) sm.pt[hc * 136 + m] = hv;   // v: [hc][m]
                    else           sm.pt[m * 136 + hc] = hv;   // q/k: [m][hc]
                }
        __syncthreads();

        if (part < 2) {
            // head-major store: [winG*8+head][t][d(16)]; float4 = 8 d elems
            f16* dst = (part == 0 ? qw : kw) + so + (size_t)idx * WIN;
            int tq = tid >> 4, hcg = tid & 15;
            int hd = hcg >> 1, d0 = (hcg & 1) * 8;
            #pragma unroll
            for (int it = 0; it < 8; ++it) {
                int m = it * 16 + tq;
                int h = h0 + (m >> 6), w = m & 63;
                int winG, t;
                if (idx == 0) { winG = b * 16 + (w >> 2); t = (h << 2) | (w & 3); }
                else          { winG = b * 16 + (h >> 2); t = ((h & 3) << 6) | w; }
                *(float4*)(dst + ((((size_t)(winG * 8 + hd)) * 256 + t) << 4) + d0) =
                    *(const float4*)&sm.pt[m * 136 + hcg * 8];
            }
        } else {
            // c-major store: [winG][hc][t]
            f16* dst = vw + so + (size_t)idx * WIN;
            int mg = tid & 15, hcq = tid >> 4;
            int row = mg >> 3, h = h0 + row;
            #pragma unroll
            for (int it = 0; it < 8; ++it) {
                int hc = it * 16 + hcq;
                if (idx == 1) {
                    int w = (mg & 7) * 8;
                    int winG = b * 16 + (h >> 2);
                    int t = ((h & 3) << 6) | w;
                    *(float4*)(dst + (((size_t)winG * 128 + hc) << 8) + t) =
                        *(const float4*)&sm.pt[hc * 136 + mg * 8];
                } else {
                    #pragma unroll
                    for (int q2 = 0; q2 < 2; ++q2) {
                        int w0 = (mg & 7) * 8 + q2 * 4;
                        int winG = b * 16 + (w0 >> 2);
                        int t = h << 2;   // +0..3 via the 4 consecutive elems
                        *(half4*)(dst + (((size_t)winG * 128 + hc) << 8) + t) =
                            *(const half4*)&sm.pt[hc * 136 + mg * 8 + q2 * 4];
                    }
                }
            }
        }
    }
}

// ---- MFMA attention + FUSED LePE dwconv3x3
// grid 4096 blocks = (winG, idx, head, shift); 256 threads; wave = q-quarter.
// LDS: kl 8KB | vl 8KB | sp 16KB (spatial V + halos for this head's 16 ch).
// co[16][260] aliases kl/vl AFTER the MFMA loop (barrier-separated).
// sp layouts (r13, 8B-aligned centers):
//   idx0: [hcl][h(64)][8]: center cols 0..3, RIGHT halo col 4, LEFT halo
//         col 7; conv col = (wp+kx-1)&7.
//   idx1: [hcl][hp(6)][80]: center cols 8..71, zero cols 7 & 72;
//         conv col = 7+w+kx.
__global__ __launch_bounds__(256) void k_attn(
    const f16* __restrict__ qw, const f16* __restrict__ kw,
    const f16* __restrict__ vw, const f16* __restrict__ wl16,
    const f16* __restrict__ bl16, f16* __restrict__ ow)
{
    const int tid = threadIdx.x;
    const int lane = tid & 63, wave = tid >> 6;
    const int g = lane >> 4, ln = lane & 15;
    const int head = blockIdx.x & 7, idx = (blockIdx.x >> 3) & 1;
    const int winG = (blockIdx.x >> 4) & 127;
    const int si = blockIdx.x >> 11;
    const size_t so = (size_t)si * SSTR;
    const int wi = winG & 15;

    __shared__ f16 smem[16384];          // 32 KB
    f16* kl = smem;                      // [kt(16)][lane(64)][4]
    f16* vl = smem + 4096;               // [kt(16)][lane(64)][4]
    f16* sp = smem + 8192;               // spatial V+halo (16 hcl)
    f16* co = smem;                      // conv out [16][260], aliases kl/vl

    const size_t cb = ((size_t)(winG * 8 + head)) << 4;   // c-major: (+d)<<8 + t
    // head-major q/k: 4096 elems per (winG,head)
    const f16* qb = qw + so + (size_t)idx * WIN + (((size_t)(winG * 8 + head)) << 12);
    const f16* kb = kw + so + (size_t)idx * WIN + (((size_t)(winG * 8 + head)) << 12);
    const f16* vb = vw + so + (size_t)idx * WIN;
    f16* ob = ow + so + (size_t)idx * WIN;

    // stage K: thread = token t; fully contiguous 32B/thread (head-major)
    // K A-frag elem = k[t=kt*16+ln][d=g*4+j]
    {
        int t = tid;
        const f16* src = kb + ((size_t)t << 4);
        float4 a = *(const float4*)src;          // d0..7
        float4 b2 = *(const float4*)(src + 8);   // d8..15
        const f16* ap = (const f16*)&a;
        const f16* bp = (const f16*)&b2;
        int kt = t >> 4, l2 = t & 15;
        *(half4*)&kl[(kt * 64 + 0 * 16 + l2) * 4] = *(const half4*)(ap);
        *(half4*)&kl[(kt * 64 + 1 * 16 + l2) * 4] = *(const half4*)(ap + 4);
        *(half4*)&kl[(kt * 64 + 2 * 16 + l2) * 4] = *(const half4*)(bp);
        *(half4*)&kl[(kt * 64 + 3 * 16 + l2) * 4] = *(const half4*)(bp + 4);
    }
    // stage V ONCE: single float4 read feeds BOTH the frag-ordered vl
    // (V^T A-frag elem = v[d=ln][t=kt*16+g*4+j]) and the conv's spatial
    // sp center (aligned: two half4 writes per float4).
    {
        const f16* src = vb + (cb << 8);
        #pragma unroll
        for (int r2 = 0; r2 < 2; ++r2) {
            int e = r2 * 256 + tid;              // float4 index 0..511
            float4 a = *(const float4*)(src + e * 8);
            const f16* ap = (const f16*)&a;
            int d = e >> 5;                      // 32 float4 per d-row
            int t0 = (e & 31) * 8;
            int kt0 = t0 >> 4, g0 = (t0 >> 2) & 3;
            *(half4*)&vl[(kt0 * 64 + g0 * 16 + d) * 4] = *(const half4*)ap;
            int t1 = t0 + 4;
            int kt1 = t1 >> 4, g1 = (t1 >> 2) & 3;
            *(half4*)&vl[(kt1 * 64 + g1 * 16 + d) * 4] = *(const half4*)(ap + 4);
            if (idx == 0) {
                // center cols 0..3: base 8-elem aligned
                int base = (d << 9) + ((t0 >> 2) << 3);
                *(half4*)&sp[base] = *(const half4*)ap;
                *(half4*)&sp[base + 8] = *(const half4*)(ap + 4);
            } else {
                // center cols 8..71 of 80-wide rows: base 8-elem aligned
                int base = d * 480 + (1 + (t0 >> 6)) * 80 + 8 + (t0 & 63);
                *(half4*)&sp[base] = *(const half4*)ap;
                *(half4*)&sp[base + 4] = *(const half4*)(ap + 4);
            }
        }
    }
    // stage conv halos (neighbor windows) + idx1 side-zero columns
    if (idx == 0) {
        for (int ii = tid; ii < 16 * 128; ii += 256) {
            int hcl = ii >> 7, j = ii & 127;
            int side = j >> 6, h = j & 63;
            f16 v = (f16)0.f;
            if (side == 0) { if (wi > 0)
                v = vb[(((size_t)(winG - 1) * 128 + head * 16 + hcl) << 8) + h * 4 + 3]; }
            else           { if (wi < 15)
                v = vb[(((size_t)(winG + 1) * 128 + head * 16 + hcl) << 8) + h * 4]; }
            sp[(hcl << 9) + (h << 3) + (side ? 4 : 7)] = v;   // left->7, right->4
        }
    } else {
        const int ROW = 80;
        for (int ii = tid; ii < 16 * 128; ii += 256) {
            int hcl = ii >> 7, j = ii & 127;
            int side = j >> 6, w = j & 63;
            f16 v = (f16)0.f;
            if (side == 0) { if (wi > 0)
                v = vb[(((size_t)(winG - 1) * 128 + head * 16 + hcl) << 8) + 192 + w]; }
            else           { if (wi < 15)
                v = vb[(((size_t)(winG + 1) * 128 + head * 16 + hcl) << 8) + w]; }
            sp[hcl * 6 * ROW + (side ? 5 : 0) * ROW + 8 + w] = v;
        }
        for (int ii = tid; ii < 16 * 6 * 2; ii += 256) {
            int hcl = ii / 12, rr = (ii % 12) >> 1, e = ii & 1;
            sp[hcl * 6 * ROW + rr * ROW + (e ? 72 : 7)] = (f16)0.f;
        }
    }

    // Q^T B-frags: B[k=d=g*4+j][n=query=ln]  (head-major: half4, wave reads
    // 16 t x 16 d = 512B fully contiguous)
    half4 qf[4];
    #pragma unroll
    for (int qt = 0; qt < 4; ++qt) {
        int t = wave * 64 + qt * 16 + ln;
        qf[qt] = *(const half4*)(qb + ((size_t)t << 4) + g * 4);
    }

    __syncthreads();

    floatx4 o[4]; float lsum[4];
    #pragma unroll
    for (int qt = 0; qt < 4; ++qt) { o[qt] = (floatx4){0.f,0.f,0.f,0.f}; lsum[qt] = 0.f; }

    for (int kt = 0; kt < 16; ++kt) {
        half4 kf = *(const half4*)&kl[(kt * 64 + lane) * 4];
        half4 vf = *(const half4*)&vl[(kt * 64 + lane) * 4];
        #pragma unroll
        for (int qt = 0; qt < 4; ++qt) {
            floatx4 sc = __builtin_amdgcn_mfma_f32_16x16x16f16(
                kf, qf[qt], (floatx4){0.f,0.f,0.f,0.f}, 0, 0, 0);
            // q pre-scaled by 0.25*log2(e): exp(s) = exp2(sc)
            float p0 = __builtin_amdgcn_exp2f(sc[0]);
            float p1 = __builtin_amdgcn_exp2f(sc[1]);
            float p2 = __builtin_amdgcn_exp2f(sc[2]);
            float p3 = __builtin_amdgcn_exp2f(sc[3]);
            lsum[qt] += (p0 + p1) + (p2 + p3);
            half4 pf = {(f16)p0, (f16)p1, (f16)p2, (f16)p3};
            o[qt] = __builtin_amdgcn_mfma_f32_16x16x16f16(vf, pf, o[qt], 0, 0, 0);
        }
    }

    __syncthreads();   // kl/vl reads done: co may overwrite them

    // LePE conv (f16 arithmetic) for this head's 16 ch: sp -> co[hcl][t]
    if (idx == 0) {
        int h = tid >> 2, wp = tid & 3;
        for (int hcl = 0; hcl < 16; ++hcl) {
            int c = hcl * 8 + head;
            f16 acc = bl16[c];
            #pragma unroll
            for (int ky = 0; ky < 3; ++ky) {
                int hh = h + ky - 1;
                if (hh < 0 || hh > 63) continue;
                #pragma unroll
                for (int kx = 0; kx < 3; ++kx)
                    acc += wl16[c * 9 + ky * 3 + kx] *
                           sp[(hcl << 9) + (hh << 3) + ((wp + kx - 1) & 7)];
            }
            co[hcl * 260 + tid] = acc;
        }
    } else {
        const int ROW = 80;
        int hloc = tid >> 6, w = tid & 63;
        for (int hcl = 0; hcl < 16; ++hcl) {
            int c = hcl * 8 + head;
            f16 acc = bl16[c];
            #pragma unroll
            for (int ky = 0; ky < 3; ++ky)
                #pragma unroll
                for (int kx = 0; kx < 3; ++kx)
                    acc += wl16[c * 9 + ky * 3 + kx] *
                           sp[hcl * 6 * ROW + (hloc + ky) * ROW + 7 + w + kx];
            co[hcl * 260 + tid] = acc;
        }
    }
    __syncthreads();   // co ready

    #pragma unroll
    for (int qt = 0; qt < 4; ++qt) {
        float l = lsum[qt];
        l += __shfl_xor(l, 16);
        l += __shfl_xor(l, 32);
        float inv = 1.f / l;
        int t = wave * 64 + qt * 16 + ln;
        #pragma unroll
        for (int r = 0; r < 4; ++r) {
            int d = g * 4 + r;
            float val = fmaf(o[qt][r], inv, (float)co[d * 260 + t]);
            ob[((cb + d) << 8) + t] = (f16)val;
        }
    }
}

// ---- combine shifts + inverse roll, single coalesced out write
// Block = 1024 consecutive out elems: oc fixed, 16 oh x 64 w, b fixed.
// idx0 working set staged via coalesced reads into padded LDS [16][68].
__global__ __launch_bounds__(256) void k_final(
    const f16* __restrict__ ow0, const f16* __restrict__ ow2,
    float* __restrict__ out)
{
    __shared__ f16 sp[2][16][68];   // 4.25 KB, +4 pad breaks 64-elem stride
    const int tid = threadIdx.x;
    const int e0 = blockIdx.x << 10;
    const int oc = (e0 >> 12) & 255, bb = e0 >> 20, oh0 = (e0 >> 6) & 63;
    const int idx = oc >> 7;

    if (idx == 0) {
        #pragma unroll
        for (int si = 0; si < 2; ++si) {
            const f16* p = si ? ow2 : ow0;
            int s = si * 2;
            int cl = ((oc & 127) - s) & 127;
            int head = cl & 7, d = cl >> 3;
            #pragma unroll
            for (int it = 0; it < 4; ++it) {
                int v = it * 256 + tid;          // 16 k-rows x 64 j
                int k = v >> 6, j = v & 63;
                int t = (((oh0 + (j >> 2) - s) & 63) << 2) | (j & 3);
                int wg = bb * 16 + k;
                sp[si][k][j] =
                    p[(((size_t)(wg * 8 + head) * 16 + d) << 8) + t];
            }
        }
        __syncthreads();
        #pragma unroll
        for (int it = 0; it < 4; ++it) {
            int e = e0 + it * 256 + tid;
            int w = e & 63, oh = (e >> 6) & 63;
            int j = ((oh - oh0) << 2) | (w & 3);
            float acc = (float)sp[0][w >> 2][j] + (float)sp[1][w >> 2][j];
            out[e] = acc;
        }
    } else {
        #pragma unroll
        for (int it = 0; it < 4; ++it) {
            int e = e0 + it * 256 + tid;
            int w = e & 63, oh = (e >> 6) & 63;
            float acc = 0.f;
            #pragma unroll
            for (int si = 0; si < 2; ++si) {
                int s = si * 2;
                const f16* p = si ? ow2 : ow0;
                int cl = ((oc & 127) - s) & 127;
                int h = (oh - s) & 63;
                int head = cl & 7, d = cl >> 3;
                int wg = bb * 16 + (h >> 2);
                int t = ((h & 3) << 6) | w;
                acc += (float)p[(size_t)WIN
                                + (((size_t)(wg * 8 + head) * 16 + d) << 8) + t];
            }
            out[e] = acc;
        }
    }
}

extern "C" void kernel_launch(void* const* d_in, const int* in_sizes, int n_in,
                              void* d_out, int out_size, void* d_ws, size_t ws_size,
                              hipStream_t stream) {
    const float* x      = (const float*)d_in[0];
    const float* w_qkv  = (const float*)d_in[1];
    const float* w_lepe = (const float*)d_in[2];
    const float* b_lepe = (const float*)d_in[3];
    float* out = (float*)d_out;

    f16* wsf = (f16*)d_ws;
    f16* wqB  = wsf;                        // 49152 + wl16 1152 + bl16 128
    f16* wl16 = wqB + 49152;
    f16* bl16 = wl16 + 1152;
    f16* base = wsf + 65536;                // per-shift regions, stride SSTR
    f16* qw   = base;
    f16* kw   = base + 2 * (size_t)WIN;
    f16* vw   = base + 4 * (size_t)WIN;
    f16* ow   = base + 8 * (size_t)WIN;
    // total: 65536 + 2*SSTR f16 = 160.1 MiB < 256 MiB ws

    k_prep<<<193, 256, 0, stream>>>(w_qkv, w_lepe, b_lepe, wqB, wl16, bl16);

    k_proj<<<dim3(32, 8, 4), 256, 0, stream>>>(x, wqB, qw, kw, vw);
    k_attn<<<4096, 256, 0, stream>>>(qw, kw, vw, wl16, bl16, ow);

    k_final<<<8192, 256, 0, stream>>>(ow, ow + (size_t)SSTR, out);
}

// Round 14
// 213.812 us; speedup vs baseline: 1.2312x; 1.2312x over previous
//
#include <hip/hip_runtime.h>
#include <hip/hip_bf16.h>

typedef _Float16 f16;
typedef _Float16 half4 __attribute__((ext_vector_type(4)));
typedef float floatx4 __attribute__((ext_vector_type(4)));

// Problem: B=8, C=256, H=W=64, sd=128, HEADS=8, hd=16, window L=256 tokens.
// idx0 = 64x4 column strips (wi = w>>2, t = h*4+(w&3)),
// idx1 = 4x64 row strips   (wi = h>>2, t = (h&3)*64+w).
// Layouts (f16), per idx:
//   qw,kw: head-major [winG*8+head][t(256)][d(16)]
//   vw,ow: c-major [winG(128)][hc(128)][t(256)]      (hc = head*16+d)
// WIN = elems per [idx] tensor = 4194304.
// BOTH shifts live simultaneously (per-shift region stride SSTR f16).
//
// LESSON (r1): XOR swizzle over a non-pow2 padded stride is NOT bijective.
// LESSON (r3/r4/r5): M-split k_proj variants all pathological. M=128 +
// (256,2) is the only well-behaved codegen point. FROZEN at 77.3us.
// LESSON (r8/r9/r13): cvt_pkrtz-via-union AND scalar-f16 conv arithmetic
// both blow VGPR (60->152 / 60->76) - f16 SCALAR ops are pattern-fragile;
// keep conv math in f32 (fmaf), f16 only for memory/MFMA operands.
// LESSON (r11/r12): k_attn is VALU-issue-bound (FETCH 148->49MB from
// head-major Q/K moved dur only -6%).
// r14 = r12 + aligned sp centers only (r13's change-2, un-bundled):
//   idx0: [hcl][h(64)][8]: center cols 0..3, RIGHT halo col 4, LEFT col 7;
//         conv col = (wp+kx-1)&7.
//   idx1: [hcl][hp(6)][80]: center cols 8..71, zero cols 7 & 72;
//         conv col = 7+w+kx.
// -> V-staging sp writes are 2x half4 (was 8 scalar).
#define WIN 4194304
#define SSTR 41943040

// ---- weight prep: wqB[part][kt][nt][lane][kj] (B-frag-ordered)
__global__ void k_prep(const float* __restrict__ wq, f16* __restrict__ wqB) {
    int D = blockIdx.x * 256 + threadIdx.x;
    if (D >= 49152) return;
    int kj = D & 3, lane = (D >> 2) & 63, nt = (D >> 8) & 7;
    int kt = (D >> 11) & 7, part = D >> 14;
    int g = lane >> 4, ln = lane & 15;
    int o = part * 128 + nt * 16 + ln;
    int k = kt * 16 + g * 4 + kj;
    wqB[D] = (f16)wq[o * 128 + k];
}

// ---- MFMA projection, pixel-row tiled: M=128 px (2 h-rows), K=128, N=384
// grid (32 row-pairs, 8 b, 2 idx x 2 shift) = 1024 blocks, 256 threads.
// LDS A-tile: chunked [kc(32)][m(128)][kj(4)] with XOR swizzle
// phys_byte = (kc*1024 + m*8 + kj*2) ^ (((m>>4)&7)<<4)  -> conflict-free
// b128 writes AND contiguous frag reads; bijective (m bits 4..6 live
// untouched in byte bits 7..9).
__global__ __launch_bounds__(256, 2) void k_proj(
    const float* __restrict__ x, const f16* __restrict__ wqB,
    f16* __restrict__ qw, f16* __restrict__ kw, f16* __restrict__ vw)
{
    const int rt = blockIdx.x, b = blockIdx.y;
    const int idx = blockIdx.z & 1, si = blockIdx.z >> 1;
    const int s = si * 2;
    const size_t so = (size_t)si * SSTR;
    const int h0 = rt * 2;
    const int tid = threadIdx.x;
    const int wave = tid >> 6, lane = tid & 63, g = lane >> 4, ln = lane & 15;

    union __align__(16) SM {
        f16 xa[32 * 128 * 4];   // 32 KB  A chunked [kc(32)][m(128)][kj(4)], swizzled
        f16 pt[128 * 136];      // 34.8 KB transpose tile, padded (no swizzle!)
    };
    __shared__ SM sm;

    // stage x -> f16 LDS: per tile, gather 4 c-rows (coalesced float4),
    // register 4x4 transpose, two swizzled b128 stores.
    {
        const int wg = tid & 31;
        const int row = wg >> 4, w4 = (wg & 15) << 2;
        const int gh = (h0 + row + s) & 63;
        const int m0 = row * 64 + w4;
        const unsigned fb = (((unsigned)m0 >> 4) & 7u) << 4;
        const float* xp = x + (((size_t)b * 256) << 12) + (gh << 6) + w4;
        char* lbase = (char*)sm.xa;
        #pragma unroll
        for (int it = 0; it < 4; ++it) {
            int cg = (tid >> 5) + it * 8;
            float4 v4[4];
            #pragma unroll
            for (int cc = 0; cc < 4; ++cc) {
                int gc = (idx * 128 + cg * 4 + cc + s) & 255;
                v4[cc] = *(const float4*)(xp + ((size_t)gc << 12));
            }
            union { half4 h[4]; float4 q[2]; } t;
            #pragma unroll
            for (int jj = 0; jj < 4; ++jj)
                t.h[jj] = (half4){
                    (f16)(((const float*)&v4[0])[jj]),
                    (f16)(((const float*)&v4[1])[jj]),
                    (f16)(((const float*)&v4[2])[jj]),
                    (f16)(((const float*)&v4[3])[jj])};
            char* p = lbase + cg * 1024;
            *(float4*)(p + (((unsigned)(m0 * 8)) ^ fb)) = t.q[0];
            *(float4*)(p + (((unsigned)(m0 * 8 + 16)) ^ fb)) = t.q[1];
        }
    }
    __syncthreads();

    // A-frags (held across parts): A[m=px][k=c], swizzled read (f uniform/instr)
    half4 af[2][8];
    #pragma unroll
    for (int mt = 0; mt < 2; ++mt) {
        int m = wave * 32 + mt * 16 + ln;
        unsigned fb = (((unsigned)m >> 4) & 7u) << 4;
        #pragma unroll
        for (int kt = 0; kt < 8; ++kt) {
            int kc = kt * 4 + g;
            af[mt][kt] = *(const half4*)((char*)sm.xa + kc * 1024 +
                                         (((unsigned)(m * 8)) ^ fb));
        }
    }

    for (int part = 0; part < 3; ++part) {
        floatx4 C[8][2];
        #pragma unroll
        for (int nt = 0; nt < 8; ++nt)
            #pragma unroll
            for (int mt = 0; mt < 2; ++mt) C[nt][mt] = (floatx4){0.f, 0.f, 0.f, 0.f};

        for (int kt = 0; kt < 8; ++kt) {
            half4 bf[8];
            #pragma unroll
            for (int nt = 0; nt < 8; ++nt)
                bf[nt] = *(const half4*)&wqB[((((part * 8 + kt) * 8 + nt) * 64) + lane) * 4];
            #pragma unroll
            for (int nt = 0; nt < 8; ++nt)
                #pragma unroll
                for (int mt = 0; mt < 2; ++mt)
                    C[nt][mt] = __builtin_amdgcn_mfma_f32_16x16x16f16(
                        af[mt][kt], bf[nt], C[nt][mt], 0, 0, 0);
        }

        // q: fold softmax scale AND log2(e) (attn uses exp2)
        const float qsc = (part == 0) ? 0.25f * 1.4426950408889634f : 1.0f;

        __syncthreads();    // xa (part0) / previous pt reads done
        #pragma unroll
        for (int nt = 0; nt < 8; ++nt)
            #pragma unroll
            for (int mt = 0; mt < 2; ++mt)
                #pragma unroll
                for (int r = 0; r < 4; ++r) {
                    int m = wave * 32 + mt * 16 + g * 4 + r;
                    int c = nt * 16 + ln;                 // part-local o
                    int hc = ((c & 7) << 4) + (c >> 3);   // head*16+d
                    f16 hv = (f16)(C[nt][mt][r] * qsc);
                    if (part == 2) sm.pt[hc * 136 + m] = hv;   // v: [hc][m]
                    else           sm.pt[m * 136 + hc] = hv;   // q/k: [m][hc]
                }
        __syncthreads();

        if (part < 2) {
            // head-major store: [winG*8+head][t][d(16)]; float4 = 8 d elems
            f16* dst = (part == 0 ? qw : kw) + so + (size_t)idx * WIN;
            int tq = tid >> 4, hcg = tid & 15;
            int hd = hcg >> 1, d0 = (hcg & 1) * 8;
            #pragma unroll
            for (int it = 0; it < 8; ++it) {
                int m = it * 16 + tq;
                int h = h0 + (m >> 6), w = m & 63;
                int winG, t;
                if (idx == 0) { winG = b * 16 + (w >> 2); t = (h << 2) | (w & 3); }
                else          { winG = b * 16 + (h >> 2); t = ((h & 3) << 6) | w; }
                *(float4*)(dst + ((((size_t)(winG * 8 + hd)) * 256 + t) << 4) + d0) =
                    *(const float4*)&sm.pt[m * 136 + hcg * 8];
            }
        } else {
            // c-major store: [winG][hc][t]
            f16* dst = vw + so + (size_t)idx * WIN;
            int mg = tid & 15, hcq = tid >> 4;
            int row = mg >> 3, h = h0 + row;
            #pragma unroll
            for (int it = 0; it < 8; ++it) {
                int hc = it * 16 + hcq;
                if (idx == 1) {
                    int w = (mg & 7) * 8;
                    int winG = b * 16 + (h >> 2);
                    int t = ((h & 3) << 6) | w;
                    *(float4*)(dst + (((size_t)winG * 128 + hc) << 8) + t) =
                        *(const float4*)&sm.pt[hc * 136 + mg * 8];
                } else {
                    #pragma unroll
                    for (int q2 = 0; q2 < 2; ++q2) {
                        int w0 = (mg & 7) * 8 + q2 * 4;
                        int winG = b * 16 + (w0 >> 2);
                        int t = h << 2;   // +0..3 via the 4 consecutive elems
                        *(half4*)(dst + (((size_t)winG * 128 + hc) << 8) + t) =
                            *(const half4*)&sm.pt[hc * 136 + mg * 8 + q2 * 4];
                    }
                }
            }
        }
    }
}

// ---- MFMA attention + FUSED LePE dwconv3x3
// grid 4096 blocks = (winG, idx, head, shift); 256 threads; wave = q-quarter.
// LDS: kl 8KB | vl 8KB | sp 16KB (spatial V + halos for this head's 16 ch).
// co[16][260] aliases kl/vl AFTER the MFMA loop (barrier-separated).
__global__ __launch_bounds__(256) void k_attn(
    const f16* __restrict__ qw, const f16* __restrict__ kw,
    const f16* __restrict__ vw, const float* __restrict__ wle,
    const float* __restrict__ ble, f16* __restrict__ ow)
{
    const int tid = threadIdx.x;
    const int lane = tid & 63, wave = tid >> 6;
    const int g = lane >> 4, ln = lane & 15;
    const int head = blockIdx.x & 7, idx = (blockIdx.x >> 3) & 1;
    const int winG = (blockIdx.x >> 4) & 127;
    const int si = blockIdx.x >> 11;
    const size_t so = (size_t)si * SSTR;
    const int wi = winG & 15;

    __shared__ f16 smem[16384];          // 32 KB
    f16* kl = smem;                      // [kt(16)][lane(64)][4]
    f16* vl = smem + 4096;               // [kt(16)][lane(64)][4]
    f16* sp = smem + 8192;               // spatial V+halo (16 hcl)
    f16* co = smem;                      // conv out [16][260], aliases kl/vl

    const size_t cb = ((size_t)(winG * 8 + head)) << 4;   // c-major: (+d)<<8 + t
    // head-major q/k: 4096 elems per (winG,head)
    const f16* qb = qw + so + (size_t)idx * WIN + (((size_t)(winG * 8 + head)) << 12);
    const f16* kb = kw + so + (size_t)idx * WIN + (((size_t)(winG * 8 + head)) << 12);
    const f16* vb = vw + so + (size_t)idx * WIN;
    f16* ob = ow + so + (size_t)idx * WIN;

    // stage K: thread = token t; fully contiguous 32B/thread (head-major)
    // K A-frag elem = k[t=kt*16+ln][d=g*4+j]
    {
        int t = tid;
        const f16* src = kb + ((size_t)t << 4);
        float4 a = *(const float4*)src;          // d0..7
        float4 b2 = *(const float4*)(src + 8);   // d8..15
        const f16* ap = (const f16*)&a;
        const f16* bp = (const f16*)&b2;
        int kt = t >> 4, l2 = t & 15;
        *(half4*)&kl[(kt * 64 + 0 * 16 + l2) * 4] = *(const half4*)(ap);
        *(half4*)&kl[(kt * 64 + 1 * 16 + l2) * 4] = *(const half4*)(ap + 4);
        *(half4*)&kl[(kt * 64 + 2 * 16 + l2) * 4] = *(const half4*)(bp);
        *(half4*)&kl[(kt * 64 + 3 * 16 + l2) * 4] = *(const half4*)(bp + 4);
    }
    // stage V ONCE: single float4 read feeds BOTH the frag-ordered vl
    // (V^T A-frag elem = v[d=ln][t=kt*16+g*4+j]) and the conv's spatial
    // sp center (aligned: two half4 writes per float4).
    {
        const f16* src = vb + (cb << 8);
        #pragma unroll
        for (int r2 = 0; r2 < 2; ++r2) {
            int e = r2 * 256 + tid;              // float4 index 0..511
            float4 a = *(const float4*)(src + e * 8);
            const f16* ap = (const f16*)&a;
            int d = e >> 5;                      // 32 float4 per d-row
            int t0 = (e & 31) * 8;
            int kt0 = t0 >> 4, g0 = (t0 >> 2) & 3;
            *(half4*)&vl[(kt0 * 64 + g0 * 16 + d) * 4] = *(const half4*)ap;
            int t1 = t0 + 4;
            int kt1 = t1 >> 4, g1 = (t1 >> 2) & 3;
            *(half4*)&vl[(kt1 * 64 + g1 * 16 + d) * 4] = *(const half4*)(ap + 4);
            if (idx == 0) {
                // center cols 0..3: base 8-elem aligned
                int base = (d << 9) + ((t0 >> 2) << 3);
                *(half4*)&sp[base] = *(const half4*)ap;
                *(half4*)&sp[base + 8] = *(const half4*)(ap + 4);
            } else {
                // center cols 8..71 of 80-wide rows: base 8-elem aligned
                int base = d * 480 + (1 + (t0 >> 6)) * 80 + 8 + (t0 & 63);
                *(half4*)&sp[base] = *(const half4*)ap;
                *(half4*)&sp[base + 4] = *(const half4*)(ap + 4);
            }
        }
    }
    // stage conv halos (neighbor windows) + idx1 side-zero columns
    if (idx == 0) {
        for (int ii = tid; ii < 16 * 128; ii += 256) {
            int hcl = ii >> 7, j = ii & 127;
            int side = j >> 6, h = j & 63;
            f16 v = (f16)0.f;
            if (side == 0) { if (wi > 0)
                v = vb[(((size_t)(winG - 1) * 128 + head * 16 + hcl) << 8) + h * 4 + 3]; }
            else           { if (wi < 15)
                v = vb[(((size_t)(winG + 1) * 128 + head * 16 + hcl) << 8) + h * 4]; }
            sp[(hcl << 9) + (h << 3) + (side ? 4 : 7)] = v;   // left->7, right->4
        }
    } else {
        const int ROW = 80;
        for (int ii = tid; ii < 16 * 128; ii += 256) {
            int hcl = ii >> 7, j = ii & 127;
            int side = j >> 6, w = j & 63;
            f16 v = (f16)0.f;
            if (side == 0) { if (wi > 0)
                v = vb[(((size_t)(winG - 1) * 128 + head * 16 + hcl) << 8) + 192 + w]; }
            else           { if (wi < 15)
                v = vb[(((size_t)(winG + 1) * 128 + head * 16 + hcl) << 8) + w]; }
            sp[hcl * 6 * ROW + (side ? 5 : 0) * ROW + 8 + w] = v;
        }
        for (int ii = tid; ii < 16 * 6 * 2; ii += 256) {
            int hcl = ii / 12, rr = (ii % 12) >> 1, e = ii & 1;
            sp[hcl * 6 * ROW + rr * ROW + (e ? 72 : 7)] = (f16)0.f;
        }
    }

    // Q^T B-frags: B[k=d=g*4+j][n=query=ln]  (head-major: half4, wave reads
    // 16 t x 16 d = 512B fully contiguous)
    half4 qf[4];
    #pragma unroll
    for (int qt = 0; qt < 4; ++qt) {
        int t = wave * 64 + qt * 16 + ln;
        qf[qt] = *(const half4*)(qb + ((size_t)t << 4) + g * 4);
    }

    __syncthreads();

    floatx4 o[4]; float lsum[4];
    #pragma unroll
    for (int qt = 0; qt < 4; ++qt) { o[qt] = (floatx4){0.f,0.f,0.f,0.f}; lsum[qt] = 0.f; }

    for (int kt = 0; kt < 16; ++kt) {
        half4 kf = *(const half4*)&kl[(kt * 64 + lane) * 4];
        half4 vf = *(const half4*)&vl[(kt * 64 + lane) * 4];
        #pragma unroll
        for (int qt = 0; qt < 4; ++qt) {
            floatx4 sc = __builtin_amdgcn_mfma_f32_16x16x16f16(
                kf, qf[qt], (floatx4){0.f,0.f,0.f,0.f}, 0, 0, 0);
            // q pre-scaled by 0.25*log2(e): exp(s) = exp2(sc)
            float p0 = __builtin_amdgcn_exp2f(sc[0]);
            float p1 = __builtin_amdgcn_exp2f(sc[1]);
            float p2 = __builtin_amdgcn_exp2f(sc[2]);
            float p3 = __builtin_amdgcn_exp2f(sc[3]);
            lsum[qt] += (p0 + p1) + (p2 + p3);
            half4 pf = {(f16)p0, (f16)p1, (f16)p2, (f16)p3};
            o[qt] = __builtin_amdgcn_mfma_f32_16x16x16f16(vf, pf, o[qt], 0, 0, 0);
        }
    }

    __syncthreads();   // kl/vl reads done: co may overwrite them

    // LePE conv (f32 math - r13 lesson) for this head's 16 ch: sp -> co
    if (idx == 0) {
        int h = tid >> 2, wp = tid & 3;
        for (int hcl = 0; hcl < 16; ++hcl) {
            int c = hcl * 8 + head;
            float acc = ble[c];
            #pragma unroll
            for (int ky = 0; ky < 3; ++ky) {
                int hh = h + ky - 1;
                if (hh < 0 || hh > 63) continue;
                #pragma unroll
                for (int kx = 0; kx < 3; ++kx)
                    acc = fmaf(wle[c * 9 + ky * 3 + kx],
                               (float)sp[(hcl << 9) + (hh << 3) + ((wp + kx - 1) & 7)],
                               acc);
            }
            co[hcl * 260 + tid] = (f16)acc;
        }
    } else {
        const int ROW = 80;
        int hloc = tid >> 6, w = tid & 63;
        for (int hcl = 0; hcl < 16; ++hcl) {
            int c = hcl * 8 + head;
            float acc = ble[c];
            #pragma unroll
            for (int ky = 0; ky < 3; ++ky)
                #pragma unroll
                for (int kx = 0; kx < 3; ++kx)
                    acc = fmaf(wle[c * 9 + ky * 3 + kx],
                               (float)sp[hcl * 6 * ROW + (hloc + ky) * ROW + 7 + w + kx],
                               acc);
            co[hcl * 260 + tid] = (f16)acc;
        }
    }
    __syncthreads();   // co ready

    #pragma unroll
    for (int qt = 0; qt < 4; ++qt) {
        float l = lsum[qt];
        l += __shfl_xor(l, 16);
        l += __shfl_xor(l, 32);
        float inv = 1.f / l;
        int t = wave * 64 + qt * 16 + ln;
        #pragma unroll
        for (int r = 0; r < 4; ++r) {
            int d = g * 4 + r;
            float val = fmaf(o[qt][r], inv, (float)co[d * 260 + t]);
            ob[((cb + d) << 8) + t] = (f16)val;
        }
    }
}

// ---- combine shifts + inverse roll, single coalesced out write
// Block = 1024 consecutive out elems: oc fixed, 16 oh x 64 w, b fixed.
// idx0 working set staged via coalesced reads into padded LDS [16][68].
__global__ __launch_bounds__(256) void k_final(
    const f16* __restrict__ ow0, const f16* __restrict__ ow2,
    float* __restrict__ out)
{
    __shared__ f16 sp[2][16][68];   // 4.25 KB, +4 pad breaks 64-elem stride
    const int tid = threadIdx.x;
    const int e0 = blockIdx.x << 10;
    const int oc = (e0 >> 12) & 255, bb = e0 >> 20, oh0 = (e0 >> 6) & 63;
    const int idx = oc >> 7;

    if (idx == 0) {
        #pragma unroll
        for (int si = 0; si < 2; ++si) {
            const f16* p = si ? ow2 : ow0;
            int s = si * 2;
            int cl = ((oc & 127) - s) & 127;
            int head = cl & 7, d = cl >> 3;
            #pragma unroll
            for (int it = 0; it < 4; ++it) {
                int v = it * 256 + tid;          // 16 k-rows x 64 j
                int k = v >> 6, j = v & 63;
                int t = (((oh0 + (j >> 2) - s) & 63) << 2) | (j & 3);
                int wg = bb * 16 + k;
                sp[si][k][j] =
                    p[(((size_t)(wg * 8 + head) * 16 + d) << 8) + t];
            }
        }
        __syncthreads();
        #pragma unroll
        for (int it = 0; it < 4; ++it) {
            int e = e0 + it * 256 + tid;
            int w = e & 63, oh = (e >> 6) & 63;
            int j = ((oh - oh0) << 2) | (w & 3);
            float acc = (float)sp[0][w >> 2][j] + (float)sp[1][w >> 2][j];
            out[e] = acc;
        }
    } else {
        #pragma unroll
        for (int it = 0; it < 4; ++it) {
            int e = e0 + it * 256 + tid;
            int w = e & 63, oh = (e >> 6) & 63;
            float acc = 0.f;
            #pragma unroll
            for (int si = 0; si < 2; ++si) {
                int s = si * 2;
                const f16* p = si ? ow2 : ow0;
                int cl = ((oc & 127) - s) & 127;
                int h = (oh - s) & 63;
                int head = cl & 7, d = cl >> 3;
                int wg = bb * 16 + (h >> 2);
                int t = ((h & 3) << 6) | w;
                acc += (float)p[(size_t)WIN
                                + (((size_t)(wg * 8 + head) * 16 + d) << 8) + t];
            }
            out[e] = acc;
        }
    }
}

extern "C" void kernel_launch(void* const* d_in, const int* in_sizes, int n_in,
                              void* d_out, int out_size, void* d_ws, size_t ws_size,
                              hipStream_t stream) {
    const float* x      = (const float*)d_in[0];
    const float* w_qkv  = (const float*)d_in[1];
    const float* w_lepe = (const float*)d_in[2];
    const float* b_lepe = (const float*)d_in[3];
    float* out = (float*)d_out;

    f16* wsf = (f16*)d_ws;
    f16* wqB  = wsf;                        // 49152 used, 65536 reserved
    f16* base = wsf + 65536;                // per-shift regions, stride SSTR
    f16* qw   = base;
    f16* kw   = base + 2 * (size_t)WIN;
    f16* vw   = base + 4 * (size_t)WIN;
    f16* ow   = base + 8 * (size_t)WIN;
    // total: 65536 + 2*SSTR f16 = 160.1 MiB < 256 MiB ws

    k_prep<<<192, 256, 0, stream>>>(w_qkv, wqB);

    k_proj<<<dim3(32, 8, 4), 256, 0, stream>>>(x, wqB, qw, kw, vw);
    k_attn<<<4096, 256, 0, stream>>>(qw, kw, vw, w_lepe, b_lepe, ow);

    k_final<<<8192, 256, 0, stream>>>(ow, ow + (size_t)SSTR, out);
}

// Round 15
// 207.896 us; speedup vs baseline: 1.2662x; 1.0285x over previous
//
#include <hip/hip_runtime.h>
#include <hip/hip_bf16.h>

typedef _Float16 f16;
typedef _Float16 half4 __attribute__((ext_vector_type(4)));
typedef float floatx4 __attribute__((ext_vector_type(4)));

// Problem: B=8, C=256, H=W=64, sd=128, HEADS=8, hd=16, window L=256 tokens.
// idx0 = 64x4 column strips (wi = w>>2, t = h*4+(w&3)),
// idx1 = 4x64 row strips   (wi = h>>2, t = (h&3)*64+w).
// Layouts (f16), per idx:
//   qw,kw: head-major [winG*8+head][t(256)][d(16)]
//   vw,ow: c-major [winG(128)][hc(128)][t(256)]      (hc = head*16+d)
// WIN = elems per [idx] tensor = 4194304.
// BOTH shifts live simultaneously (per-shift region stride SSTR f16).
//
// LESSON (r1): XOR swizzle over a non-pow2 padded stride is NOT bijective.
// LESSON (r3/r4/r5): M-split k_proj variants all pathological. M=128 +
// (256,2) is the only well-behaved codegen point. FROZEN at 77.3us.
// LESSON (r8/r9/r13): cvt_pkrtz-via-union AND scalar-f16 conv arithmetic
// both blow VGPR - f16 SCALAR ops are pattern-fragile; keep conv math in
// f32 (fmaf), f16 only for memory/MFMA operands.
// LESSON (r11/r12): k_attn is VALU-issue-bound (FETCH 148->49MB moved dur
// only -6%). r14: aligned sp centers (2x half4 staging writes) = -2us.
// r15: softmax denominator via ones-MFMA on the idle matrix pipe -
// lacc[qt] = mfma(ones, pf, lacc[qt]) replaces 192 v_add_f32 + 8 shuffles;
// every lane then holds the full denominator in lacc[qt][0].
#define WIN 4194304
#define SSTR 41943040

// ---- weight prep: wqB[part][kt][nt][lane][kj] (B-frag-ordered)
__global__ void k_prep(const float* __restrict__ wq, f16* __restrict__ wqB) {
    int D = blockIdx.x * 256 + threadIdx.x;
    if (D >= 49152) return;
    int kj = D & 3, lane = (D >> 2) & 63, nt = (D >> 8) & 7;
    int kt = (D >> 11) & 7, part = D >> 14;
    int g = lane >> 4, ln = lane & 15;
    int o = part * 128 + nt * 16 + ln;
    int k = kt * 16 + g * 4 + kj;
    wqB[D] = (f16)wq[o * 128 + k];
}

// ---- MFMA projection, pixel-row tiled: M=128 px (2 h-rows), K=128, N=384
// grid (32 row-pairs, 8 b, 2 idx x 2 shift) = 1024 blocks, 256 threads.
// LDS A-tile: chunked [kc(32)][m(128)][kj(4)] with XOR swizzle
// phys_byte = (kc*1024 + m*8 + kj*2) ^ (((m>>4)&7)<<4)  -> conflict-free
// b128 writes AND contiguous frag reads; bijective (m bits 4..6 live
// untouched in byte bits 7..9).
__global__ __launch_bounds__(256, 2) void k_proj(
    const float* __restrict__ x, const f16* __restrict__ wqB,
    f16* __restrict__ qw, f16* __restrict__ kw, f16* __restrict__ vw)
{
    const int rt = blockIdx.x, b = blockIdx.y;
    const int idx = blockIdx.z & 1, si = blockIdx.z >> 1;
    const int s = si * 2;
    const size_t so = (size_t)si * SSTR;
    const int h0 = rt * 2;
    const int tid = threadIdx.x;
    const int wave = tid >> 6, lane = tid & 63, g = lane >> 4, ln = lane & 15;

    union __align__(16) SM {
        f16 xa[32 * 128 * 4];   // 32 KB  A chunked [kc(32)][m(128)][kj(4)], swizzled
        f16 pt[128 * 136];      // 34.8 KB transpose tile, padded (no swizzle!)
    };
    __shared__ SM sm;

    // stage x -> f16 LDS: per tile, gather 4 c-rows (coalesced float4),
    // register 4x4 transpose, two swizzled b128 stores.
    {
        const int wg = tid & 31;
        const int row = wg >> 4, w4 = (wg & 15) << 2;
        const int gh = (h0 + row + s) & 63;
        const int m0 = row * 64 + w4;
        const unsigned fb = (((unsigned)m0 >> 4) & 7u) << 4;
        const float* xp = x + (((size_t)b * 256) << 12) + (gh << 6) + w4;
        char* lbase = (char*)sm.xa;
        #pragma unroll
        for (int it = 0; it < 4; ++it) {
            int cg = (tid >> 5) + it * 8;
            float4 v4[4];
            #pragma unroll
            for (int cc = 0; cc < 4; ++cc) {
                int gc = (idx * 128 + cg * 4 + cc + s) & 255;
                v4[cc] = *(const float4*)(xp + ((size_t)gc << 12));
            }
            union { half4 h[4]; float4 q[2]; } t;
            #pragma unroll
            for (int jj = 0; jj < 4; ++jj)
                t.h[jj] = (half4){
                    (f16)(((const float*)&v4[0])[jj]),
                    (f16)(((const float*)&v4[1])[jj]),
                    (f16)(((const float*)&v4[2])[jj]),
                    (f16)(((const float*)&v4[3])[jj])};
            char* p = lbase + cg * 1024;
            *(float4*)(p + (((unsigned)(m0 * 8)) ^ fb)) = t.q[0];
            *(float4*)(p + (((unsigned)(m0 * 8 + 16)) ^ fb)) = t.q[1];
        }
    }
    __syncthreads();

    // A-frags (held across parts): A[m=px][k=c], swizzled read (f uniform/instr)
    half4 af[2][8];
    #pragma unroll
    for (int mt = 0; mt < 2; ++mt) {
        int m = wave * 32 + mt * 16 + ln;
        unsigned fb = (((unsigned)m >> 4) & 7u) << 4;
        #pragma unroll
        for (int kt = 0; kt < 8; ++kt) {
            int kc = kt * 4 + g;
            af[mt][kt] = *(const half4*)((char*)sm.xa + kc * 1024 +
                                         (((unsigned)(m * 8)) ^ fb));
        }
    }

    for (int part = 0; part < 3; ++part) {
        floatx4 C[8][2];
        #pragma unroll
        for (int nt = 0; nt < 8; ++nt)
            #pragma unroll
            for (int mt = 0; mt < 2; ++mt) C[nt][mt] = (floatx4){0.f, 0.f, 0.f, 0.f};

        for (int kt = 0; kt < 8; ++kt) {
            half4 bf[8];
            #pragma unroll
            for (int nt = 0; nt < 8; ++nt)
                bf[nt] = *(const half4*)&wqB[((((part * 8 + kt) * 8 + nt) * 64) + lane) * 4];
            #pragma unroll
            for (int nt = 0; nt < 8; ++nt)
                #pragma unroll
                for (int mt = 0; mt < 2; ++mt)
                    C[nt][mt] = __builtin_amdgcn_mfma_f32_16x16x16f16(
                        af[mt][kt], bf[nt], C[nt][mt], 0, 0, 0);
        }

        // q: fold softmax scale AND log2(e) (attn uses exp2)
        const float qsc = (part == 0) ? 0.25f * 1.4426950408889634f : 1.0f;

        __syncthreads();    // xa (part0) / previous pt reads done
        #pragma unroll
        for (int nt = 0; nt < 8; ++nt)
            #pragma unroll
            for (int mt = 0; mt < 2; ++mt)
                #pragma unroll
                for (int r = 0; r < 4; ++r) {
                    int m = wave * 32 + mt * 16 + g * 4 + r;
                    int c = nt * 16 + ln;                 // part-local o
                    int hc = ((c & 7) << 4) + (c >> 3);   // head*16+d
                    f16 hv = (f16)(C[nt][mt][r] * qsc);
                    if (part == 2) sm.pt[hc * 136 + m] = hv;   // v: [hc][m]
                    else           sm.pt[m * 136 + hc] = hv;   // q/k: [m][hc]
                }
        __syncthreads();

        if (part < 2) {
            // head-major store: [winG*8+head][t][d(16)]; float4 = 8 d elems
            f16* dst = (part == 0 ? qw : kw) + so + (size_t)idx * WIN;
            int tq = tid >> 4, hcg = tid & 15;
            int hd = hcg >> 1, d0 = (hcg & 1) * 8;
            #pragma unroll
            for (int it = 0; it < 8; ++it) {
                int m = it * 16 + tq;
                int h = h0 + (m >> 6), w = m & 63;
                int winG, t;
                if (idx == 0) { winG = b * 16 + (w >> 2); t = (h << 2) | (w & 3); }
                else          { winG = b * 16 + (h >> 2); t = ((h & 3) << 6) | w; }
                *(float4*)(dst + ((((size_t)(winG * 8 + hd)) * 256 + t) << 4) + d0) =
                    *(const float4*)&sm.pt[m * 136 + hcg * 8];
            }
        } else {
            // c-major store: [winG][hc][t]
            f16* dst = vw + so + (size_t)idx * WIN;
            int mg = tid & 15, hcq = tid >> 4;
            int row = mg >> 3, h = h0 + row;
            #pragma unroll
            for (int it = 0; it < 8; ++it) {
                int hc = it * 16 + hcq;
                if (idx == 1) {
                    int w = (mg & 7) * 8;
                    int winG = b * 16 + (h >> 2);
                    int t = ((h & 3) << 6) | w;
                    *(float4*)(dst + (((size_t)winG * 128 + hc) << 8) + t) =
                        *(const float4*)&sm.pt[hc * 136 + mg * 8];
                } else {
                    #pragma unroll
                    for (int q2 = 0; q2 < 2; ++q2) {
                        int w0 = (mg & 7) * 8 + q2 * 4;
                        int winG = b * 16 + (w0 >> 2);
                        int t = h << 2;   // +0..3 via the 4 consecutive elems
                        *(half4*)(dst + (((size_t)winG * 128 + hc) << 8) + t) =
                            *(const half4*)&sm.pt[hc * 136 + mg * 8 + q2 * 4];
                    }
                }
            }
        }
    }
}

// ---- MFMA attention + FUSED LePE dwconv3x3
// grid 4096 blocks = (winG, idx, head, shift); 256 threads; wave = q-quarter.
// LDS: kl 8KB | vl 8KB | sp 16KB (spatial V + halos for this head's 16 ch).
// co[16][260] aliases kl/vl AFTER the MFMA loop (barrier-separated).
__global__ __launch_bounds__(256) void k_attn(
    const f16* __restrict__ qw, const f16* __restrict__ kw,
    const f16* __restrict__ vw, const float* __restrict__ wle,
    const float* __restrict__ ble, f16* __restrict__ ow)
{
    const int tid = threadIdx.x;
    const int lane = tid & 63, wave = tid >> 6;
    const int g = lane >> 4, ln = lane & 15;
    const int head = blockIdx.x & 7, idx = (blockIdx.x >> 3) & 1;
    const int winG = (blockIdx.x >> 4) & 127;
    const int si = blockIdx.x >> 11;
    const size_t so = (size_t)si * SSTR;
    const int wi = winG & 15;

    __shared__ f16 smem[16384];          // 32 KB
    f16* kl = smem;                      // [kt(16)][lane(64)][4]
    f16* vl = smem + 4096;               // [kt(16)][lane(64)][4]
    f16* sp = smem + 8192;               // spatial V+halo (16 hcl)
    f16* co = smem;                      // conv out [16][260], aliases kl/vl

    const size_t cb = ((size_t)(winG * 8 + head)) << 4;   // c-major: (+d)<<8 + t
    // head-major q/k: 4096 elems per (winG,head)
    const f16* qb = qw + so + (size_t)idx * WIN + (((size_t)(winG * 8 + head)) << 12);
    const f16* kb = kw + so + (size_t)idx * WIN + (((size_t)(winG * 8 + head)) << 12);
    const f16* vb = vw + so + (size_t)idx * WIN;
    f16* ob = ow + so + (size_t)idx * WIN;

    // stage K: thread = token t; fully contiguous 32B/thread (head-major)
    // K A-frag elem = k[t=kt*16+ln][d=g*4+j]
    {
        int t = tid;
        const f16* src = kb + ((size_t)t << 4);
        float4 a = *(const float4*)src;          // d0..7
        float4 b2 = *(const float4*)(src + 8);   // d8..15
        const f16* ap = (const f16*)&a;
        const f16* bp = (const f16*)&b2;
        int kt = t >> 4, l2 = t & 15;
        *(half4*)&kl[(kt * 64 + 0 * 16 + l2) * 4] = *(const half4*)(ap);
        *(half4*)&kl[(kt * 64 + 1 * 16 + l2) * 4] = *(const half4*)(ap + 4);
        *(half4*)&kl[(kt * 64 + 2 * 16 + l2) * 4] = *(const half4*)(bp);
        *(half4*)&kl[(kt * 64 + 3 * 16 + l2) * 4] = *(const half4*)(bp + 4);
    }
    // stage V ONCE: single float4 read feeds BOTH the frag-ordered vl
    // (V^T A-frag elem = v[d=ln][t=kt*16+g*4+j]) and the conv's spatial
    // sp center (aligned: two half4 writes per float4).
    {
        const f16* src = vb + (cb << 8);
        #pragma unroll
        for (int r2 = 0; r2 < 2; ++r2) {
            int e = r2 * 256 + tid;              // float4 index 0..511
            float4 a = *(const float4*)(src + e * 8);
            const f16* ap = (const f16*)&a;
            int d = e >> 5;                      // 32 float4 per d-row
            int t0 = (e & 31) * 8;
            int kt0 = t0 >> 4, g0 = (t0 >> 2) & 3;
            *(half4*)&vl[(kt0 * 64 + g0 * 16 + d) * 4] = *(const half4*)ap;
            int t1 = t0 + 4;
            int kt1 = t1 >> 4, g1 = (t1 >> 2) & 3;
            *(half4*)&vl[(kt1 * 64 + g1 * 16 + d) * 4] = *(const half4*)(ap + 4);
            if (idx == 0) {
                // center cols 0..3: base 8-elem aligned
                int base = (d << 9) + ((t0 >> 2) << 3);
                *(half4*)&sp[base] = *(const half4*)ap;
                *(half4*)&sp[base + 8] = *(const half4*)(ap + 4);
            } else {
                // center cols 8..71 of 80-wide rows: base 8-elem aligned
                int base = d * 480 + (1 + (t0 >> 6)) * 80 + 8 + (t0 & 63);
                *(half4*)&sp[base] = *(const half4*)ap;
                *(half4*)&sp[base + 4] = *(const half4*)(ap + 4);
            }
        }
    }
    // stage conv halos (neighbor windows) + idx1 side-zero columns
    if (idx == 0) {
        for (int ii = tid; ii < 16 * 128; ii += 256) {
            int hcl = ii >> 7, j = ii & 127;
            int side = j >> 6, h = j & 63;
            f16 v = (f16)0.f;
            if (side == 0) { if (wi > 0)
                v = vb[(((size_t)(winG - 1) * 128 + head * 16 + hcl) << 8) + h * 4 + 3]; }
            else           { if (wi < 15)
                v = vb[(((size_t)(winG + 1) * 128 + head * 16 + hcl) << 8) + h * 4]; }
            sp[(hcl << 9) + (h << 3) + (side ? 4 : 7)] = v;   // left->7, right->4
        }
    } else {
        const int ROW = 80;
        for (int ii = tid; ii < 16 * 128; ii += 256) {
            int hcl = ii >> 7, j = ii & 127;
            int side = j >> 6, w = j & 63;
            f16 v = (f16)0.f;
            if (side == 0) { if (wi > 0)
                v = vb[(((size_t)(winG - 1) * 128 + head * 16 + hcl) << 8) + 192 + w]; }
            else           { if (wi < 15)
                v = vb[(((size_t)(winG + 1) * 128 + head * 16 + hcl) << 8) + w]; }
            sp[hcl * 6 * ROW + (side ? 5 : 0) * ROW + 8 + w] = v;
        }
        for (int ii = tid; ii < 16 * 6 * 2; ii += 256) {
            int hcl = ii / 12, rr = (ii % 12) >> 1, e = ii & 1;
            sp[hcl * 6 * ROW + rr * ROW + (e ? 72 : 7)] = (f16)0.f;
        }
    }

    // Q^T B-frags: B[k=d=g*4+j][n=query=ln]  (head-major: half4, wave reads
    // 16 t x 16 d = 512B fully contiguous)
    half4 qf[4];
    #pragma unroll
    for (int qt = 0; qt < 4; ++qt) {
        int t = wave * 64 + qt * 16 + ln;
        qf[qt] = *(const half4*)(qb + ((size_t)t << 4) + g * 4);
    }

    __syncthreads();

    floatx4 o[4]; floatx4 lacc[4];
    #pragma unroll
    for (int qt = 0; qt < 4; ++qt) {
        o[qt] = (floatx4){0.f,0.f,0.f,0.f};
        lacc[qt] = (floatx4){0.f,0.f,0.f,0.f};
    }
    const half4 onef = {(f16)1.f, (f16)1.f, (f16)1.f, (f16)1.f};

    for (int kt = 0; kt < 16; ++kt) {
        half4 kf = *(const half4*)&kl[(kt * 64 + lane) * 4];
        half4 vf = *(const half4*)&vl[(kt * 64 + lane) * 4];
        #pragma unroll
        for (int qt = 0; qt < 4; ++qt) {
            floatx4 sc = __builtin_amdgcn_mfma_f32_16x16x16f16(
                kf, qf[qt], (floatx4){0.f,0.f,0.f,0.f}, 0, 0, 0);
            // q pre-scaled by 0.25*log2(e): exp(s) = exp2(sc)
            float p0 = __builtin_amdgcn_exp2f(sc[0]);
            float p1 = __builtin_amdgcn_exp2f(sc[1]);
            float p2 = __builtin_amdgcn_exp2f(sc[2]);
            float p3 = __builtin_amdgcn_exp2f(sc[3]);
            half4 pf = {(f16)p0, (f16)p1, (f16)p2, (f16)p3};
            // denominator on the (idle) MFMA pipe: C[m][q] = sum_k P[k][q];
            // all rows identical -> lacc[qt][0] = full denominator for query ln
            lacc[qt] = __builtin_amdgcn_mfma_f32_16x16x16f16(
                onef, pf, lacc[qt], 0, 0, 0);
            o[qt] = __builtin_amdgcn_mfma_f32_16x16x16f16(vf, pf, o[qt], 0, 0, 0);
        }
    }

    __syncthreads();   // kl/vl reads done: co may overwrite them

    // LePE conv (f32 math - r13 lesson) for this head's 16 ch: sp -> co
    if (idx == 0) {
        int h = tid >> 2, wp = tid & 3;
        for (int hcl = 0; hcl < 16; ++hcl) {
            int c = hcl * 8 + head;
            float acc = ble[c];
            #pragma unroll
            for (int ky = 0; ky < 3; ++ky) {
                int hh = h + ky - 1;
                if (hh < 0 || hh > 63) continue;
                #pragma unroll
                for (int kx = 0; kx < 3; ++kx)
                    acc = fmaf(wle[c * 9 + ky * 3 + kx],
                               (float)sp[(hcl << 9) + (hh << 3) + ((wp + kx - 1) & 7)],
                               acc);
            }
            co[hcl * 260 + tid] = (f16)acc;
        }
    } else {
        const int ROW = 80;
        int hloc = tid >> 6, w = tid & 63;
        for (int hcl = 0; hcl < 16; ++hcl) {
            int c = hcl * 8 + head;
            float acc = ble[c];
            #pragma unroll
            for (int ky = 0; ky < 3; ++ky)
                #pragma unroll
                for (int kx = 0; kx < 3; ++kx)
                    acc = fmaf(wle[c * 9 + ky * 3 + kx],
                               (float)sp[hcl * 6 * ROW + (hloc + ky) * ROW + 7 + w + kx],
                               acc);
            co[hcl * 260 + tid] = (f16)acc;
        }
    }
    __syncthreads();   // co ready

    #pragma unroll
    for (int qt = 0; qt < 4; ++qt) {
        float inv = 1.f / lacc[qt][0];
        int t = wave * 64 + qt * 16 + ln;
        #pragma unroll
        for (int r = 0; r < 4; ++r) {
            int d = g * 4 + r;
            float val = fmaf(o[qt][r], inv, (float)co[d * 260 + t]);
            ob[((cb + d) << 8) + t] = (f16)val;
        }
    }
}

// ---- combine shifts + inverse roll, single coalesced out write
// Block = 1024 consecutive out elems: oc fixed, 16 oh x 64 w, b fixed.
// idx0 working set staged via coalesced reads into padded LDS [16][68].
__global__ __launch_bounds__(256) void k_final(
    const f16* __restrict__ ow0, const f16* __restrict__ ow2,
    float* __restrict__ out)
{
    __shared__ f16 sp[2][16][68];   // 4.25 KB, +4 pad breaks 64-elem stride
    const int tid = threadIdx.x;
    const int e0 = blockIdx.x << 10;
    const int oc = (e0 >> 12) & 255, bb = e0 >> 20, oh0 = (e0 >> 6) & 63;
    const int idx = oc >> 7;

    if (idx == 0) {
        #pragma unroll
        for (int si = 0; si < 2; ++si) {
            const f16* p = si ? ow2 : ow0;
            int s = si * 2;
            int cl = ((oc & 127) - s) & 127;
            int head = cl & 7, d = cl >> 3;
            #pragma unroll
            for (int it = 0; it < 4; ++it) {
                int v = it * 256 + tid;          // 16 k-rows x 64 j
                int k = v >> 6, j = v & 63;
                int t = (((oh0 + (j >> 2) - s) & 63) << 2) | (j & 3);
                int wg = bb * 16 + k;
                sp[si][k][j] =
                    p[(((size_t)(wg * 8 + head) * 16 + d) << 8) + t];
            }
        }
        __syncthreads();
        #pragma unroll
        for (int it = 0; it < 4; ++it) {
            int e = e0 + it * 256 + tid;
            int w = e & 63, oh = (e >> 6) & 63;
            int j = ((oh - oh0) << 2) | (w & 3);
            float acc = (float)sp[0][w >> 2][j] + (float)sp[1][w >> 2][j];
            out[e] = acc;
        }
    } else {
        #pragma unroll
        for (int it = 0; it < 4; ++it) {
            int e = e0 + it * 256 + tid;
            int w = e & 63, oh = (e >> 6) & 63;
            float acc = 0.f;
            #pragma unroll
            for (int si = 0; si < 2; ++si) {
                int s = si * 2;
                const f16* p = si ? ow2 : ow0;
                int cl = ((oc & 127) - s) & 127;
                int h = (oh - s) & 63;
                int head = cl & 7, d = cl >> 3;
                int wg = bb * 16 + (h >> 2);
                int t = ((h & 3) << 6) | w;
                acc += (float)p[(size_t)WIN
                                + (((size_t)(wg * 8 + head) * 16 + d) << 8) + t];
            }
            out[e] = acc;
        }
    }
}

extern "C" void kernel_launch(void* const* d_in, const int* in_sizes, int n_in,
                              void* d_out, int out_size, void* d_ws, size_t ws_size,
                              hipStream_t stream) {
    const float* x      = (const float*)d_in[0];
    const float* w_qkv  = (const float*)d_in[1];
    const float* w_lepe = (const float*)d_in[2];
    const float* b_lepe = (const float*)d_in[3];
    float* out = (float*)d_out;

    f16* wsf = (f16*)d_ws;
    f16* wqB  = wsf;                        // 49152 used, 65536 reserved
    f16* base = wsf + 65536;                // per-shift regions, stride SSTR
    f16* qw   = base;
    f16* kw   = base + 2 * (size_t)WIN;
    f16* vw   = base + 4 * (size_t)WIN;
    f16* ow   = base + 8 * (size_t)WIN;
    // total: 65536 + 2*SSTR f16 = 160.1 MiB < 256 MiB ws

    k_prep<<<192, 256, 0, stream>>>(w_qkv, wqB);

    k_proj<<<dim3(32, 8, 4), 256, 0, stream>>>(x, wqB, qw, kw, vw);
    k_attn<<<4096, 256, 0, stream>>>(qw, kw, vw, w_lepe, b_lepe, ow);

    k_final<<<8192, 256, 0, stream>>>(ow, ow + (size_t)SSTR, out);
}